// Round 3
// baseline (138.738 us; speedup 1.0000x reference)
//
#include <hip/hip_runtime.h>

#define T_LEN 16384
#define VAR_EPS 1e-5f

typedef float v4 __attribute__((ext_vector_type(4)));
#define NTL(P) __builtin_nontemporal_load(P)

// ---------------------------------------------------------------------------
// Stage 1: 2 blocks per row (half-rows), 256 threads. Per thread: 8 float4
// per stream, consumed with a rolling 4-pair prefetch window (~8 dwordx4 nt
// loads in flight). Register budget deliberately < 64 VGPR so the CU can
// hold the full 32-wave occupancy tier: theory is the read wall is a per-CU
// outstanding-line pool scaled by resident waves.
// Each block writes its 5 partial moments non-atomically to its own slot:
// moments[(row*2 + half)*8 + k]. No memset, no atomics.
// ---------------------------------------------------------------------------

#define ACC(P,Q)                                              \
    sp  += (P.x + P.y) + (P.z + P.w);                         \
    st  += (Q.x + Q.y) + (Q.z + Q.w);                         \
    spp += P.x*P.x + P.y*P.y + P.z*P.z + P.w*P.w;             \
    stt += Q.x*Q.x + Q.y*Q.y + Q.z*Q.z + Q.w*Q.w;             \
    spt += P.x*Q.x + P.y*Q.y + P.z*Q.z + P.w*Q.w;

__global__ __launch_bounds__(256) void pearson_half_kernel(
    const float* __restrict__ pred, const float* __restrict__ target,
    float* __restrict__ moments)
{
    const int blk  = blockIdx.x;
    const int row  = blk >> 1;
    const int half = blk & 1;
    const int tid  = threadIdx.x;

    // half-row = 8192 floats = 2048 float4 per stream
    const v4* __restrict__ p4 =
        (const v4*)(pred   + (size_t)row * T_LEN) + half * 2048;
    const v4* __restrict__ t4 =
        (const v4*)(target + (size_t)row * T_LEN) + half * 2048;

    float sp = 0.f, st = 0.f, spp = 0.f, stt = 0.f, spt = 0.f;

    // Rolling 4-pair window: prefetch 4 (p,t) pairs, then acc+reload each
    // slot once, then drain. Steady state: 8 nt loads outstanding.
    v4 p0 = NTL(p4 + tid);        v4 t0 = NTL(t4 + tid);
    v4 p1 = NTL(p4 + tid + 256);  v4 t1 = NTL(t4 + tid + 256);
    v4 p2 = NTL(p4 + tid + 512);  v4 t2 = NTL(t4 + tid + 512);
    v4 p3 = NTL(p4 + tid + 768);  v4 t3 = NTL(t4 + tid + 768);

    ACC(p0, t0); p0 = NTL(p4 + tid + 1024); t0 = NTL(t4 + tid + 1024);
    ACC(p1, t1); p1 = NTL(p4 + tid + 1280); t1 = NTL(t4 + tid + 1280);
    ACC(p2, t2); p2 = NTL(p4 + tid + 1536); t2 = NTL(t4 + tid + 1536);
    ACC(p3, t3); p3 = NTL(p4 + tid + 1792); t3 = NTL(t4 + tid + 1792);
    ACC(p0, t0);
    ACC(p1, t1);
    ACC(p2, t2);
    ACC(p3, t3);

    // 64-lane wave reduction (5 moments).
    #pragma unroll
    for (int off = 32; off > 0; off >>= 1) {
        sp  += __shfl_down(sp,  off);
        st  += __shfl_down(st,  off);
        spp += __shfl_down(spp, off);
        stt += __shfl_down(stt, off);
        spt += __shfl_down(spt, off);
    }

    // Cross-wave combine (4 waves) via LDS, then one non-atomic store.
    __shared__ float ws[4][8];
    const int wid = tid >> 6;
    if ((tid & 63) == 0) {
        ws[wid][0] = sp;  ws[wid][1] = st;  ws[wid][2] = spp;
        ws[wid][3] = stt; ws[wid][4] = spt;
    }
    __syncthreads();

    if (tid == 0) {
        float* m = moments + (size_t)blk * 8;
        m[0] = ws[0][0] + ws[1][0] + ws[2][0] + ws[3][0];
        m[1] = ws[0][1] + ws[1][1] + ws[2][1] + ws[3][1];
        m[2] = ws[0][2] + ws[1][2] + ws[2][2] + ws[3][2];
        m[3] = ws[0][3] + ws[1][3] + ws[2][3] + ws[3][3];
        m[4] = ws[0][4] + ws[1][4] + ws[2][4] + ws[3][4];
    }
}

// ---------------------------------------------------------------------------
// Stage 2: one block, 1024 threads -> one row each; combine the two half-row
// moment sets, compute per-row loss, reduce to mean.
// ---------------------------------------------------------------------------
__global__ __launch_bounds__(1024) void pearson_final_kernel(
    const float* __restrict__ moments, float* __restrict__ out, int B)
{
    const int tid = threadIdx.x;
    float loss_sum = 0.f;

    for (int r = tid; r < B; r += 1024) {
        const float* m0 = moments + (size_t)r * 16;
        const float* m1 = m0 + 8;
        float S_p  = m0[0] + m1[0];
        float S_t  = m0[1] + m1[1];
        float S_pp = m0[2] + m1[2];
        float S_tt = m0[3] + m1[3];
        float S_pt = m0[4] + m1[4];

        const float T   = (float)T_LEN;
        const float inv = 1.0f / T;
        float cp2 = S_pp - S_p * S_p * inv;
        float ct2 = S_tt - S_t * S_t * inv;
        float num = S_pt - S_p * S_t * inv;

        float var_p = cp2 / (T - 1.0f);
        float var_t = ct2 / (T - 1.0f);
        float denom = sqrtf(cp2 * ct2);
        float safe  = (denom > 0.0f) ? denom : 1.0f;
        float corr  = num / safe;
        bool valid = (var_p > VAR_EPS) && (var_t > VAR_EPS) &&
                     (denom > 0.0f) && !isnan(corr);
        loss_sum += valid ? (1.0f - corr) : 1.0f;
    }

    #pragma unroll
    for (int off = 32; off > 0; off >>= 1)
        loss_sum += __shfl_down(loss_sum, off);

    __shared__ float ws[16];
    if ((tid & 63) == 0) ws[tid >> 6] = loss_sum;
    __syncthreads();

    if (tid == 0) {
        float tot = 0.f;
        #pragma unroll
        for (int w = 0; w < 16; ++w) tot += ws[w];
        out[0] = tot / (float)B;
    }
}

extern "C" void kernel_launch(void* const* d_in, const int* in_sizes, int n_in,
                              void* d_out, int out_size, void* d_ws, size_t ws_size,
                              hipStream_t stream) {
    const float* pred   = (const float*)d_in[0];
    const float* target = (const float*)d_in[1];
    float* out     = (float*)d_out;
    float* moments = (float*)d_ws;              // B*16 floats, fully overwritten

    const int B = in_sizes[0] / T_LEN;

    pearson_half_kernel<<<B * 2, 256, 0, stream>>>(pred, target, moments);
    pearson_final_kernel<<<1, 1024, 0, stream>>>(moments, out, B);
}

// Round 5
// 137.161 us; speedup vs baseline: 1.0115x; 1.0115x over previous
//
#include <hip/hip_runtime.h>

#define T_LEN 16384
#define VAR_EPS 1e-5f

typedef float v4 __attribute__((ext_vector_type(4)));
#define NTL(P) __builtin_nontemporal_load(P)

// ---------------------------------------------------------------------------
// Stage 1: one block per row, 256 threads. 16 float4 per thread per stream,
// consumed through a rolling 4-slot (p,t)-pair pipeline: after the prolog,
// each ACC of slot s immediately reissues the next load into s, so the wave
// keeps ~8 nt loads in flight CONTINUOUSLY for its whole life (vs the
// burst-wait-die pattern of R1-R3, which time-averages to half depth and
// idles the issue path during drain). Fully unrolled -> all slot indices
// static (no scratch). VGPR budget ~50.
// ---------------------------------------------------------------------------

#define ACC(P,Q)                                              \
    sp  += (P.x + P.y) + (P.z + P.w);                         \
    st  += (Q.x + Q.y) + (Q.z + Q.w);                         \
    spp += P.x*P.x + P.y*P.y + P.z*P.z + P.w*P.w;             \
    stt += Q.x*Q.x + Q.y*Q.y + Q.z*Q.z + Q.w*Q.w;             \
    spt += P.x*Q.x + P.y*Q.y + P.z*Q.z + P.w*Q.w;

__global__ __launch_bounds__(256) void pearson_row_kernel(
    const float* __restrict__ pred, const float* __restrict__ target,
    float* __restrict__ moments)
{
    const int row = blockIdx.x;
    const int tid = threadIdx.x;

    const v4* __restrict__ p4 = (const v4*)(pred   + (size_t)row * T_LEN);
    const v4* __restrict__ t4 = (const v4*)(target + (size_t)row * T_LEN);

    float sp = 0.f, st = 0.f, spp = 0.f, stt = 0.f, spt = 0.f;

    v4 P[4], Q[4];

    // Prolog: fill the 4-slot window (8 loads in flight).
    #pragma unroll
    for (int s = 0; s < 4; ++s) {
        P[s] = NTL(p4 + tid + 256 * s);
        Q[s] = NTL(t4 + tid + 256 * s);
    }

    // Steady state: consume slot i&3, immediately refill it from step i+4.
    // 12 iterations, fully unrolled -> static indices, counted vmcnt waits.
    #pragma unroll
    for (int i = 0; i < 12; ++i) {
        ACC(P[i & 3], Q[i & 3]);
        P[i & 3] = NTL(p4 + tid + 256 * (i + 4));
        Q[i & 3] = NTL(t4 + tid + 256 * (i + 4));
    }

    // Drain.
    #pragma unroll
    for (int i = 12; i < 16; ++i) {
        ACC(P[i & 3], Q[i & 3]);
    }

    // 64-lane wave reduction (5 moments).
    #pragma unroll
    for (int off = 32; off > 0; off >>= 1) {
        sp  += __shfl_down(sp,  off);
        st  += __shfl_down(st,  off);
        spp += __shfl_down(spp, off);
        stt += __shfl_down(stt, off);
        spt += __shfl_down(spt, off);
    }

    // Cross-wave combine (4 waves) via LDS, one non-atomic store per row.
    __shared__ float ws[4][8];
    const int wid = tid >> 6;
    if ((tid & 63) == 0) {
        ws[wid][0] = sp;  ws[wid][1] = st;  ws[wid][2] = spp;
        ws[wid][3] = stt; ws[wid][4] = spt;
    }
    __syncthreads();

    if (tid == 0) {
        float* m = moments + (size_t)row * 8;
        m[0] = ws[0][0] + ws[1][0] + ws[2][0] + ws[3][0];
        m[1] = ws[0][1] + ws[1][1] + ws[2][1] + ws[3][1];
        m[2] = ws[0][2] + ws[1][2] + ws[2][2] + ws[3][2];
        m[3] = ws[0][3] + ws[1][3] + ws[2][3] + ws[3][3];
        m[4] = ws[0][4] + ws[1][4] + ws[2][4] + ws[3][4];
    }
}

// ---------------------------------------------------------------------------
// Stage 2: one block, 1024 threads -> one row each; per-row loss, then mean.
// ---------------------------------------------------------------------------
__global__ __launch_bounds__(1024) void pearson_final_kernel(
    const float* __restrict__ moments, float* __restrict__ out, int B)
{
    const int tid = threadIdx.x;
    float loss_sum = 0.f;

    for (int r = tid; r < B; r += 1024) {
        const float* m = moments + (size_t)r * 8;
        float S_p  = m[0];
        float S_t  = m[1];
        float S_pp = m[2];
        float S_tt = m[3];
        float S_pt = m[4];

        const float T   = (float)T_LEN;
        const float inv = 1.0f / T;
        float cp2 = S_pp - S_p * S_p * inv;
        float ct2 = S_tt - S_t * S_t * inv;
        float num = S_pt - S_p * S_t * inv;

        float var_p = cp2 / (T - 1.0f);
        float var_t = ct2 / (T - 1.0f);
        float denom = sqrtf(cp2 * ct2);
        float safe  = (denom > 0.0f) ? denom : 1.0f;
        float corr  = num / safe;
        bool valid = (var_p > VAR_EPS) && (var_t > VAR_EPS) &&
                     (denom > 0.0f) && !isnan(corr);
        loss_sum += valid ? (1.0f - corr) : 1.0f;
    }

    #pragma unroll
    for (int off = 32; off > 0; off >>= 1)
        loss_sum += __shfl_down(loss_sum, off);

    __shared__ float ws[16];
    if ((tid & 63) == 0) ws[tid >> 6] = loss_sum;
    __syncthreads();

    if (tid == 0) {
        float tot = 0.f;
        #pragma unroll
        for (int w = 0; w < 16; ++w) tot += ws[w];
        out[0] = tot / (float)B;
    }
}

extern "C" void kernel_launch(void* const* d_in, const int* in_sizes, int n_in,
                              void* d_out, int out_size, void* d_ws, size_t ws_size,
                              hipStream_t stream) {
    const float* pred   = (const float*)d_in[0];
    const float* target = (const float*)d_in[1];
    float* out     = (float*)d_out;
    float* moments = (float*)d_ws;              // B*8 floats, fully overwritten

    const int B = in_sizes[0] / T_LEN;

    pearson_row_kernel<<<B, 256, 0, stream>>>(pred, target, moments);
    pearson_final_kernel<<<1, 1024, 0, stream>>>(moments, out, B);
}